// Round 10
// baseline (931.156 us; speedup 1.0000x reference)
//
#include <hip/hip_runtime.h>
#include <hip/hip_bf16.h>
#include <math.h>

#define B_DIM 8
#define C_DIM 256
#define N_DIM 2048
#define CQ 64

#define TM 64
#define TN 64
#define TK 16

#define NT 32  // pv n-tile

using short8 = __attribute__((ext_vector_type(8))) short;
using f32x4 = __attribute__((ext_vector_type(4))) float;

__device__ __forceinline__ unsigned short f2bf(float x) {
  union { float f; unsigned int u; } c; c.f = x;
  unsigned int r = c.u + 0x7fffu + ((c.u >> 16) & 1u);
  return (unsigned short)(r >> 16);
}
__device__ __forceinline__ float bf2f(unsigned short u) {
  union { unsigned int ui; float f; } c; c.ui = ((unsigned int)u) << 16;
  return c.f;
}

// split fp32 -> (hi, lo) bf16 pair: v ~= hi + lo
__global__ void split_kernel(const float* __restrict__ src, unsigned short* __restrict__ hi,
                             unsigned short* __restrict__ lo, int count) {
  int i = blockIdx.x * 256 + threadIdx.x;
  if (i < count) {
    float v = src[i];
    unsigned short h = f2bf(v);
    hi[i] = h;
    lo[i] = f2bf(v - bf2f(h));
  }
}

// pos[b,c,n] = sum_i w[c,i]*xyz[b,n,i]
__global__ void pos_kernel(const float* __restrict__ w, const float* __restrict__ xyz,
                           float* __restrict__ pos) {
  int n = blockIdx.x * blockDim.x + threadIdx.x;
  int c = blockIdx.y;
  int b = blockIdx.z;
  const float* xp = xyz + ((long long)b * N_DIM + n) * 3;
  pos[((long long)b * C_DIM + c) * N_DIM + n] =
      w[c * 3 + 0] * xp[0] + w[c * 3 + 1] * xp[1] + w[c * 3 + 2] * xp[2];
}

// fp32 VALU GEMM (kept only for the small q projection, M=64)
__global__ void gemm_wx(const float* __restrict__ W,
                        const float* __restrict__ X, long long sxB,
                        const float* __restrict__ Xadd, long long saB,
                        const float* __restrict__ bias,
                        const float* __restrict__ bng, const float* __restrict__ bnb,
                        const float* __restrict__ bnm, const float* __restrict__ bnv,
                        const float* __restrict__ Res, long long srB,
                        float* __restrict__ Y, unsigned short* __restrict__ Ybf,
                        long long syB, int M, int K) {
  const int N = N_DIM;
  int b = blockIdx.z;
  int m0 = blockIdx.y * TM;
  int n0 = blockIdx.x * TN;
  int t = threadIdx.x;
  int tx = t & 15, ty = t >> 4;
  __shared__ float As[TK][TM + 1];
  __shared__ float Bs[TK][TN];
  float acc[4][4] = {};
  const float* Xb = X + (long long)b * sxB;
  const float* Ab = Xadd ? Xadd + (long long)b * saB : nullptr;
  for (int k0 = 0; k0 < K; k0 += TK) {
#pragma unroll
    for (int v = 0; v < 4; v++) {
      int l = t * 4 + v;
      int i = l >> 4, k = l & 15;
      As[k][i] = W[(long long)(m0 + i) * K + k0 + k];
    }
#pragma unroll
    for (int v = 0; v < 4; v++) {
      int l = t * 4 + v;
      int k = l >> 6, j = l & 63;
      float x = Xb[(long long)(k0 + k) * N + n0 + j];
      if (Ab) x += Ab[(long long)(k0 + k) * N + n0 + j];
      Bs[k][j] = x;
    }
    __syncthreads();
#pragma unroll
    for (int k = 0; k < TK; k++) {
      float a[4], bb[4];
#pragma unroll
      for (int ii = 0; ii < 4; ii++) a[ii] = As[k][ty * 4 + ii];
#pragma unroll
      for (int jj = 0; jj < 4; jj++) bb[jj] = Bs[k][tx * 4 + jj];
#pragma unroll
      for (int ii = 0; ii < 4; ii++)
#pragma unroll
        for (int jj = 0; jj < 4; jj++)
          acc[ii][jj] = fmaf(a[ii], bb[jj], acc[ii][jj]);
    }
    __syncthreads();
  }
#pragma unroll
  for (int ii = 0; ii < 4; ii++) {
    int m = m0 + ty * 4 + ii;
    float sh = bias ? bias[m] : 0.f;
    bool dobn = (bng != nullptr);
    float bnsc = 0.f, bnsh = 0.f;
    if (dobn) {
      bnsc = bng[m] * rsqrtf(bnv[m] + 1e-5f);
      bnsh = bnb[m] - bnm[m] * bnsc;
    }
#pragma unroll
    for (int jj = 0; jj < 4; jj++) {
      int n = n0 + tx * 4 + jj;
      float v = acc[ii][jj] + sh;
      if (dobn) v = fmaxf(v * bnsc + bnsh, 0.f);
      if (Res) v += Res[(long long)b * srB + (long long)m * N + n];
      if (Ybf)
        Ybf[(long long)b * syB + (long long)m * N + n] = f2bf(v);
      else
        Y[(long long)b * syB + (long long)m * N + n] = v;
    }
  }
}

// Y[b,m,n] = epi( sum_k W[m,k]*(X[b,k,n]+Xadd) ) via split-bf16 MFMA.
// XLO=true: 3 products (near-fp32). XLO=false: X hi-only (2 products) for bf16 outs.
template <bool XLO>
__global__ __launch_bounds__(256) void gemm_mfma(
    const unsigned short* __restrict__ Whi, const unsigned short* __restrict__ Wlo,
    const float* __restrict__ X, long long sxB,
    const float* __restrict__ Xadd, long long saB,
    const float* __restrict__ bias,
    const float* __restrict__ bng, const float* __restrict__ bnb,
    const float* __restrict__ bnm, const float* __restrict__ bnv,
    const float* __restrict__ Res, long long srB,
    float* __restrict__ Y, unsigned short* __restrict__ Ybf, long long syB) {
  const int N = N_DIM, K = C_DIM;
  int b = blockIdx.z;
  int m0 = blockIdx.y * 128;
  int n0 = blockIdx.x * 64;
  int t = threadIdx.x;
  int w = t >> 6, l = t & 63;
  int lr = l & 15, lk = l >> 4;
  int j = t & 63, dq = t >> 6;   // B staging: col j, k-16-group dq
  int ar = t >> 3, as_ = t & 7;  // A staging: row-slot, k-octet

  __shared__ __align__(16) char Ah[128 * 128];  // [128 m][64 k] bf16, swizzled
  __shared__ __align__(16) char Al[128 * 128];
  __shared__ __align__(16) char Bh[64 * 128];  // [64 n][64 k] bf16, swizzled
  __shared__ __align__(16) char Bl[XLO ? 64 * 128 : 16];

  const float* Xb = X + (long long)b * sxB;
  const float* Adb = Xadd ? Xadd + (long long)b * saB : nullptr;

  f32x4 acc[2][4];
#pragma unroll
  for (int i = 0; i < 2; i++)
#pragma unroll
    for (int jq = 0; jq < 4; jq++) acc[i][jq] = f32x4{0.f, 0.f, 0.f, 0.f};

  for (int k0 = 0; k0 < K; k0 += 64) {
    short8 wh[4], wl[4];
#pragma unroll
    for (int it = 0; it < 4; it++) {
      int r = it * 32 + ar;
      wh[it] = *(const short8*)(Whi + (long long)(m0 + r) * K + k0 + as_ * 8);
      wl[it] = *(const short8*)(Wlo + (long long)(m0 + r) * K + k0 + as_ * 8);
    }
    float v[16];
#pragma unroll
    for (int i = 0; i < 16; i++) {
      float x = Xb[(long long)(k0 + dq * 16 + i) * N + n0 + j];
      if (Adb) x += Adb[(long long)(k0 + dq * 16 + i) * N + n0 + j];
      v[i] = x;
    }
    unsigned int ph[8], pl[8];
#pragma unroll
    for (int i = 0; i < 8; i++) {
      unsigned short h0 = f2bf(v[2 * i]), h1 = f2bf(v[2 * i + 1]);
      ph[i] = (unsigned int)h0 | ((unsigned int)h1 << 16);
      if (XLO) {
        unsigned short l0 = f2bf(v[2 * i] - bf2f(h0)), l1 = f2bf(v[2 * i + 1] - bf2f(h1));
        pl[i] = (unsigned int)l0 | ((unsigned int)l1 << 16);
      }
    }
#pragma unroll
    for (int it = 0; it < 4; it++) {
      int r = it * 32 + ar;
      *(short8*)(Ah + r * 128 + ((as_ ^ (r & 7)) << 4)) = wh[it];
      *(short8*)(Al + r * 128 + ((as_ ^ (r & 7)) << 4)) = wl[it];
    }
    {
      int o0 = dq * 2, o1 = dq * 2 + 1;
      *(uint4*)(Bh + j * 128 + ((o0 ^ (j & 7)) << 4)) = make_uint4(ph[0], ph[1], ph[2], ph[3]);
      *(uint4*)(Bh + j * 128 + ((o1 ^ (j & 7)) << 4)) = make_uint4(ph[4], ph[5], ph[6], ph[7]);
      if (XLO) {
        *(uint4*)(Bl + j * 128 + ((o0 ^ (j & 7)) << 4)) = make_uint4(pl[0], pl[1], pl[2], pl[3]);
        *(uint4*)(Bl + j * 128 + ((o1 ^ (j & 7)) << 4)) = make_uint4(pl[4], pl[5], pl[6], pl[7]);
      }
    }
    __syncthreads();
#pragma unroll
    for (int sub = 0; sub < 2; sub++) {
      short8 ah[2], al2[2], bh[4], bl[4];
#pragma unroll
      for (int mi = 0; mi < 2; mi++) {
        int ra = w * 32 + mi * 16 + lr;
        ah[mi] = *(const short8*)(Ah + ra * 128 + (((sub * 4 + lk) ^ (ra & 7)) << 4));
        al2[mi] = *(const short8*)(Al + ra * 128 + (((sub * 4 + lk) ^ (ra & 7)) << 4));
      }
#pragma unroll
      for (int ni = 0; ni < 4; ni++) {
        int rb = ni * 16 + lr;
        bh[ni] = *(const short8*)(Bh + rb * 128 + (((sub * 4 + lk) ^ (rb & 7)) << 4));
        if (XLO) bl[ni] = *(const short8*)(Bl + rb * 128 + (((sub * 4 + lk) ^ (rb & 7)) << 4));
      }
#pragma unroll
      for (int mi = 0; mi < 2; mi++)
#pragma unroll
        for (int ni = 0; ni < 4; ni++) {
          acc[mi][ni] = __builtin_amdgcn_mfma_f32_16x16x32_bf16(ah[mi], bh[ni], acc[mi][ni], 0, 0, 0);
          if (XLO)
            acc[mi][ni] = __builtin_amdgcn_mfma_f32_16x16x32_bf16(ah[mi], bl[ni], acc[mi][ni], 0, 0, 0);
          acc[mi][ni] = __builtin_amdgcn_mfma_f32_16x16x32_bf16(al2[mi], bh[ni], acc[mi][ni], 0, 0, 0);
        }
    }
    __syncthreads();
  }
#pragma unroll
  for (int mi = 0; mi < 2; mi++) {
#pragma unroll
    for (int jj = 0; jj < 4; jj++) {
      int m = m0 + w * 32 + mi * 16 + lk * 4 + jj;
      float sh = bias ? bias[m] : 0.f;
      bool dobn = (bng != nullptr);
      float bnsc = 0.f, bnsh = 0.f;
      if (dobn) {
        bnsc = bng[m] * rsqrtf(bnv[m] + 1e-5f);
        bnsh = bnb[m] - bnm[m] * bnsc;
      }
#pragma unroll
      for (int ni = 0; ni < 4; ni++) {
        int n = n0 + ni * 16 + lr;
        float vv = acc[mi][ni][jj] + sh;
        if (dobn) vv = fmaxf(vv * bnsc + bnsh, 0.f);
        if (Res) vv += Res[(long long)b * srB + (long long)m * N + n];
        if (Ybf)
          Ybf[(long long)b * syB + (long long)m * N + n] = f2bf(vv);
        else
          Y[(long long)b * syB + (long long)m * N + n] = vv;
      }
    }
  }
}

// E[b,r,c] = sum_d q[b,d,r]*q[b,d,c] via split-bf16 MFMA. 64x64 tile, K=CQ=64.
// Also emits per-(row, c-tile) online-softmax partials (m_t, s_t) to Epart.
__global__ __launch_bounds__(256) void energy_mfma(const float* __restrict__ q,
                                                   float* __restrict__ E,
                                                   float2* __restrict__ Epart) {
  const int N = N_DIM;
  int b = blockIdx.z;
  int r0 = blockIdx.y * 64;
  int c0 = blockIdx.x * 64;
  int t = threadIdx.x;
  int w = t >> 6, l = t & 63;
  int lr = l & 15, lk = l >> 4;
  int j = t & 63, dq = t >> 6;

  __shared__ __align__(16) char Ah[64 * 128];
  __shared__ __align__(16) char Al[64 * 128];
  __shared__ __align__(16) char Bh[64 * 128];
  __shared__ __align__(16) char Bl[64 * 128];

  const float* qb = q + (long long)b * CQ * N;
  {
    float va[16], vb[16];
#pragma unroll
    for (int i = 0; i < 16; i++) {
      va[i] = qb[(long long)(dq * 16 + i) * N + r0 + j];
      vb[i] = qb[(long long)(dq * 16 + i) * N + c0 + j];
    }
    unsigned int pah[8], pal[8], pbh[8], pbl[8];
#pragma unroll
    for (int i = 0; i < 8; i++) {
      unsigned short h0 = f2bf(va[2 * i]), h1 = f2bf(va[2 * i + 1]);
      unsigned short l0 = f2bf(va[2 * i] - bf2f(h0)), l1 = f2bf(va[2 * i + 1] - bf2f(h1));
      pah[i] = (unsigned int)h0 | ((unsigned int)h1 << 16);
      pal[i] = (unsigned int)l0 | ((unsigned int)l1 << 16);
      unsigned short g0 = f2bf(vb[2 * i]), g1 = f2bf(vb[2 * i + 1]);
      unsigned short m0_ = f2bf(vb[2 * i] - bf2f(g0)), m1 = f2bf(vb[2 * i + 1] - bf2f(g1));
      pbh[i] = (unsigned int)g0 | ((unsigned int)g1 << 16);
      pbl[i] = (unsigned int)m0_ | ((unsigned int)m1 << 16);
    }
    int o0 = dq * 2, o1 = dq * 2 + 1;
    *(uint4*)(Ah + j * 128 + ((o0 ^ (j & 7)) << 4)) = make_uint4(pah[0], pah[1], pah[2], pah[3]);
    *(uint4*)(Ah + j * 128 + ((o1 ^ (j & 7)) << 4)) = make_uint4(pah[4], pah[5], pah[6], pah[7]);
    *(uint4*)(Al + j * 128 + ((o0 ^ (j & 7)) << 4)) = make_uint4(pal[0], pal[1], pal[2], pal[3]);
    *(uint4*)(Al + j * 128 + ((o1 ^ (j & 7)) << 4)) = make_uint4(pal[4], pal[5], pal[6], pal[7]);
    *(uint4*)(Bh + j * 128 + ((o0 ^ (j & 7)) << 4)) = make_uint4(pbh[0], pbh[1], pbh[2], pbh[3]);
    *(uint4*)(Bh + j * 128 + ((o1 ^ (j & 7)) << 4)) = make_uint4(pbh[4], pbh[5], pbh[6], pbh[7]);
    *(uint4*)(Bl + j * 128 + ((o0 ^ (j & 7)) << 4)) = make_uint4(pbl[0], pbl[1], pbl[2], pbl[3]);
    *(uint4*)(Bl + j * 128 + ((o1 ^ (j & 7)) << 4)) = make_uint4(pbl[4], pbl[5], pbl[6], pbl[7]);
  }
  __syncthreads();

  f32x4 acc[4];
#pragma unroll
  for (int i = 0; i < 4; i++) acc[i] = f32x4{0.f, 0.f, 0.f, 0.f};
#pragma unroll
  for (int sub = 0; sub < 2; sub++) {
    int ra = w * 16 + lr;
    short8 ah = *(const short8*)(Ah + ra * 128 + (((sub * 4 + lk) ^ (ra & 7)) << 4));
    short8 al = *(const short8*)(Al + ra * 128 + (((sub * 4 + lk) ^ (ra & 7)) << 4));
    short8 bh[4], bl[4];
#pragma unroll
    for (int ni = 0; ni < 4; ni++) {
      int rb = ni * 16 + lr;
      bh[ni] = *(const short8*)(Bh + rb * 128 + (((sub * 4 + lk) ^ (rb & 7)) << 4));
      bl[ni] = *(const short8*)(Bl + rb * 128 + (((sub * 4 + lk) ^ (rb & 7)) << 4));
    }
#pragma unroll
    for (int ni = 0; ni < 4; ni++) {
      acc[ni] = __builtin_amdgcn_mfma_f32_16x16x32_bf16(ah, bh[ni], acc[ni], 0, 0, 0);
      acc[ni] = __builtin_amdgcn_mfma_f32_16x16x32_bf16(ah, bl[ni], acc[ni], 0, 0, 0);
      acc[ni] = __builtin_amdgcn_mfma_f32_16x16x32_bf16(al, bh[ni], acc[ni], 0, 0, 0);
    }
  }
  long long base = (long long)b * N * N;
#pragma unroll
  for (int ni = 0; ni < 4; ni++)
#pragma unroll
    for (int jj = 0; jj < 4; jj++)
      E[base + (long long)(r0 + w * 16 + lk * 4 + jj) * N + c0 + ni * 16 + lr] = acc[ni][jj];

  // per-row partial softmax stats over this 64-col tile
  const long long BNr = (long long)B_DIM * N_DIM;
#pragma unroll
  for (int jj = 0; jj < 4; jj++) {
    float m = fmaxf(fmaxf(acc[0][jj], acc[1][jj]), fmaxf(acc[2][jj], acc[3][jj]));
#pragma unroll
    for (int msk = 1; msk < 16; msk <<= 1) m = fmaxf(m, __shfl_xor(m, msk, 64));
    float s = 0.f;
#pragma unroll
    for (int ni = 0; ni < 4; ni++) s += __expf(acc[ni][jj] - m);
#pragma unroll
    for (int msk = 1; msk < 16; msk <<= 1) s += __shfl_xor(s, msk, 64);
    if (lr == 0) {
      long long row = (long long)b * N + r0 + w * 16 + lk * 4 + jj;
      Epart[(long long)(c0 >> 6) * BNr + row] = make_float2(m, s);
    }
  }
}

// combine 32 per-tile partials per row -> rmax, rinv
__global__ void rowstats2(const float2* __restrict__ Epart, float* __restrict__ rmax,
                          float* __restrict__ rinv) {
  const long long BNr = (long long)B_DIM * N_DIM;
  int rloc = threadIdx.x & 63, qd = threadIdx.x >> 6;
  long long row = (long long)blockIdx.x * 64 + rloc;
  float2 v[8];
  float m = -3.4e38f;
#pragma unroll
  for (int i = 0; i < 8; i++) {
    v[i] = Epart[(long long)(qd * 8 + i) * BNr + row];
    m = fmaxf(m, v[i].x);
  }
  float s = 0.f;
#pragma unroll
  for (int i = 0; i < 8; i++) s += v[i].y * __expf(v[i].x - m);
  __shared__ float sm[4][64], ss[4][64];
  sm[qd][rloc] = m;
  ss[qd][rloc] = s;
  __syncthreads();
  if (qd == 0) {
    float M = fmaxf(fmaxf(sm[0][rloc], sm[1][rloc]), fmaxf(sm[2][rloc], sm[3][rloc]));
    float S = ss[0][rloc] * __expf(sm[0][rloc] - M) + ss[1][rloc] * __expf(sm[1][rloc] - M) +
              ss[2][rloc] * __expf(sm[2][rloc] - M) + ss[3][rloc] * __expf(sm[3][rloc] - M);
    rmax[row] = M;
    rinv[row] = 1.0f / S;
  }
}

// D[b,c,n] = Hprev - (val @ att)/colsum; att built on the fly from E rows (symmetry).
// 512 threads / 8 waves, 2-DEEP register pipeline: loads for tile i+2 are issued
// at tile i and consumed at tile i+1's stage -> E-stream HBM latency fully hidden.
#define PV_LOAD(ev, rv, iv, ar, kb)                                          \
  {                                                                          \
    ev = *(const float4*)(Ebr + (kb) + kl);                                  \
    rv = *(const float4*)(rm + (kb) + kl);                                   \
    iv = *(const float4*)(ri + (kb) + kl);                                   \
    _Pragma("unroll") for (int it = 0; it < 4; it++) {                       \
      int idx = it * 512 + t;                                                \
      int r = idx >> 3, s = idx & 7;                                         \
      ar[it] = *(const short8*)(vb + (long long)r * N + (kb) + s * 8);       \
    }                                                                        \
  }

#define PV_STAGE(ev, rv, iv, ar)                                             \
  {                                                                          \
    float a0 = __expf(ev.x - rv.x) * iv.x;                                   \
    float a1 = __expf(ev.y - rv.y) * iv.y;                                   \
    float a2 = __expf(ev.z - rv.z) * iv.z;                                   \
    float a3 = __expf(ev.w - rv.w) * iv.w;                                   \
    unsigned short u0 = f2bf(a0), u1 = f2bf(a1), u2 = f2bf(a2), u3 = f2bf(a3);\
    cs += bf2f(u0) + bf2f(u1) + bf2f(u2) + bf2f(u3);                         \
    uint2 pk;                                                                \
    pk.x = (unsigned int)u0 | ((unsigned int)u1 << 16);                      \
    pk.y = (unsigned int)u2 | ((unsigned int)u3 << 16);                      \
    *(uint2*)(Bs + brow * 128 +                                              \
              ((((kl >> 3) ^ (brow & 7)) << 4) | ((kl & 7) * 2))) = pk;      \
    _Pragma("unroll") for (int it = 0; it < 4; it++) {                       \
      int idx = it * 512 + t;                                                \
      int r = idx >> 3, s = idx & 7;                                         \
      *(short8*)(As + r * 128 + ((s ^ (r & 7)) << 4)) = ar[it];              \
    }                                                                        \
  }

#define PV_COMPUTE()                                                         \
  _Pragma("unroll") for (int sub = 0; sub < 2; sub++) {                      \
    short8 bq[2];                                                            \
    _Pragma("unroll") for (int ni = 0; ni < 2; ni++) {                       \
      int rn = ni * 16 + lr;                                                 \
      bq[ni] = *(const short8*)(Bs + rn * 128 +                              \
                                (((sub * 4 + lk) ^ (rn & 7)) << 4));         \
    }                                                                        \
    _Pragma("unroll") for (int mi = 0; mi < 2; mi++) {                       \
      int ra = w * 32 + mi * 16 + lr;                                        \
      short8 af = *(const short8*)(As + ra * 128 +                           \
                                   (((sub * 4 + lk) ^ (ra & 7)) << 4));      \
      _Pragma("unroll") for (int ni = 0; ni < 2; ni++)                       \
          acc[mi][ni] = __builtin_amdgcn_mfma_f32_16x16x32_bf16(             \
              af, bq[ni], acc[mi][ni], 0, 0, 0);                             \
    }                                                                        \
  }

__global__ __launch_bounds__(512, 4) void pv_mfma(
    const unsigned short* __restrict__ valbf,
    const float* __restrict__ E,
    const float* __restrict__ rmax, const float* __restrict__ rinv,
    const float* __restrict__ Hprev, long long shB, float* __restrict__ D) {
  const int N = N_DIM;
  int b = blockIdx.z;
  int n0 = blockIdx.x * NT;
  int t = threadIdx.x;
  int w = t >> 6, l = t & 63;
  int lr = l & 15, lk = l >> 4;
  int brow = t >> 4, kq = t & 15;  // B-build: n-row 0..31, k-quad 0..15

  __shared__ __align__(16) char As[C_DIM * 128];  // 32 KB val tile
  __shared__ __align__(16) char Bs[NT * 128];     // 4 KB P tile
  __shared__ float csfin[NT];

  const unsigned short* vb = valbf + (long long)b * C_DIM * N;
  const float* Ebr = E + ((long long)b * N + n0 + brow) * N;
  const float* rm = rmax + (long long)b * N;
  const float* ri = rinv + (long long)b * N;

  f32x4 acc[2][2];
#pragma unroll
  for (int i = 0; i < 2; i++)
#pragma unroll
    for (int jq = 0; jq < 2; jq++) acc[i][jq] = f32x4{0.f, 0.f, 0.f, 0.f};
  float cs = 0.f;
  const int kl = kq * 4;

  // 2-deep prologue: tile 0 -> set0, tile 1 -> set1
  float4 ev0, rv0, iv0, ev1, rv1, iv1;
  short8 ar0[4], ar1[4];
  PV_LOAD(ev0, rv0, iv0, ar0, 0);
  PV_LOAD(ev1, rv1, iv1, ar1, 64);

  for (int k0 = 0; k0 < N; k0 += 128) {
    // ---- even tile (set0) ----
    __syncthreads();  // prior compute's As/Bs reads complete
    PV_STAGE(ev0, rv0, iv0, ar0);
    __syncthreads();
    if (k0 + 128 < N) PV_LOAD(ev0, rv0, iv0, ar0, k0 + 128);  // tile i+2
    PV_COMPUTE();
    // ---- odd tile (set1) ----
    __syncthreads();
    PV_STAGE(ev1, rv1, iv1, ar1);
    __syncthreads();
    if (k0 + 192 < N) PV_LOAD(ev1, rv1, iv1, ar1, k0 + 192);  // tile i+3
    PV_COMPUTE();
  }

  // colsum: 16 threads per brow are consecutive lanes (kq = l&15) -> xor-reduce
  cs += __shfl_xor(cs, 1, 64);
  cs += __shfl_xor(cs, 2, 64);
  cs += __shfl_xor(cs, 4, 64);
  cs += __shfl_xor(cs, 8, 64);
  if (kq == 0) csfin[brow] = 1.0f / (1e-9f + cs);
  __syncthreads();

  const float* Hb = Hprev + (long long)b * shB;
  float* Db = D + (long long)b * C_DIM * N;
#pragma unroll
  for (int mi = 0; mi < 2; mi++) {
#pragma unroll
    for (int ni = 0; ni < 2; ni++) {
#pragma unroll
      for (int jj = 0; jj < 4; jj++) {
        int cr = w * 32 + mi * 16 + lk * 4 + jj;
        int ml = ni * 16 + lr;
        float xr = acc[mi][ni][jj] * csfin[ml];
        Db[(long long)cr * N + n0 + ml] = Hb[(long long)cr * N + n0 + ml] - xr;
      }
    }
  }
}

extern "C" void kernel_launch(void* const* d_in, const int* in_sizes, int n_in,
                              void* d_out, int out_size, void* d_ws, size_t ws_size,
                              hipStream_t stream) {
  const float* x = (const float*)d_in[0];
  const float* xyz = (const float*)d_in[1];
  const float* conv1_w = (const float*)d_in[2];
  const float* convpos_w = (const float*)d_in[3];
  const float* bn1_g = (const float*)d_in[4];
  const float* bn1_b = (const float*)d_in[5];
  const float* bn1_m = (const float*)d_in[6];
  const float* bn1_v = (const float*)d_in[7];
  const float* Wqk = (const float*)d_in[8];   // [4,64,256]
  const float* Wv = (const float*)d_in[9];    // [4,256,256]
  const float* bv = (const float*)d_in[10];   // [4,256]
  const float* Wt = (const float*)d_in[11];   // [4,256,256]
  const float* bt = (const float*)d_in[12];   // [4,256]
  const float* bng = (const float*)d_in[13];
  const float* bnb = (const float*)d_in[14];
  const float* bnm = (const float*)d_in[15];
  const float* bnv = (const float*)d_in[16];
  float* out = (float*)d_out;

  const long long BCN = (long long)B_DIM * C_DIM * N_DIM;
  const long long CN = (long long)C_DIM * N_DIM;
  const long long BN = (long long)B_DIM * N_DIM;
  const int WSZ = C_DIM * C_DIM;  // 65536
  float* ws = (float*)d_ws;
  float* pos = ws;                                       // BCN
  float* h0 = pos + BCN;                                 // BCN
  float* qbuf = h0 + BCN;                                // B*CQ*N
  float* dbuf = qbuf + (long long)B_DIM * CQ * N_DIM;    // BCN
  float* rmax = dbuf + BCN;                              // B*N
  float* rinv = rmax + BN;                               // B*N
  unsigned short* valbf = (unsigned short*)(rinv + BN);  // BCN bf16
  unsigned short* whi = valbf + BCN;                     // 9*65536 bf16
  unsigned short* wlo = whi + 9 * WSZ;                   // 9*65536 bf16
  float2* Epart = (float2*)(wlo + 9 * WSZ);              // 32 * B*N float2 (4 MB)
  float* E = (float*)(Epart + 32 * BN);                  // B*N*N

  // whi/wlo layout: [0]=conv1, [1..4]=Wv_i, [5..8]=Wt_i
  unsigned short* c1hi = whi;
  unsigned short* c1lo = wlo;
  unsigned short* wvhi = whi + WSZ;
  unsigned short* wvlo = wlo + WSZ;
  unsigned short* wthi = whi + 5 * WSZ;
  unsigned short* wtlo = wlo + 5 * WSZ;

  dim3 blk(256);

  split_kernel<<<dim3(WSZ / 256), blk, 0, stream>>>(conv1_w, c1hi, c1lo, WSZ);
  split_kernel<<<dim3(4 * WSZ / 256), blk, 0, stream>>>(Wv, wvhi, wvlo, 4 * WSZ);
  split_kernel<<<dim3(4 * WSZ / 256), blk, 0, stream>>>(Wt, wthi, wtlo, 4 * WSZ);

  pos_kernel<<<dim3(N_DIM / 256, C_DIM, B_DIM), blk, 0, stream>>>(convpos_w, xyz, pos);

  // h0 = relu(bn1(conv1_w @ x))   (3-product split MFMA)
  gemm_mfma<true><<<dim3(N_DIM / 64, 2, B_DIM), blk, 0, stream>>>(
      c1hi, c1lo, x, CN, nullptr, 0, nullptr,
      bn1_g, bn1_b, bn1_m, bn1_v, nullptr, 0, h0, nullptr, CN);

  for (int i = 0; i < 4; i++) {
    const float* hp = (i == 0) ? h0 : out + (long long)(i - 1) * CN;
    long long shp = (i == 0) ? CN : 4 * CN;

    // q = Wqk_i @ (h + pos)   (fp32 VALU, exact)
    gemm_wx<<<dim3(N_DIM / TN, CQ / TM, B_DIM), blk, 0, stream>>>(
        Wqk + (long long)i * CQ * C_DIM, hp, shp, pos, CN, nullptr,
        nullptr, nullptr, nullptr, nullptr, nullptr, 0,
        qbuf, nullptr, (long long)CQ * N_DIM, CQ, C_DIM);

    // val = Wv_i @ (h + pos) + bv_i  (2-product: output is bf16-rounded anyway)
    gemm_mfma<false><<<dim3(N_DIM / 64, 2, B_DIM), blk, 0, stream>>>(
        wvhi + (long long)i * WSZ, wvlo + (long long)i * WSZ, hp, shp, pos, CN,
        bv + i * C_DIM, nullptr, nullptr, nullptr, nullptr, nullptr, 0,
        nullptr, valbf, CN);

    // E = q^T q  + per-tile softmax partials
    energy_mfma<<<dim3(N_DIM / 64, N_DIM / 64, B_DIM), blk, 0, stream>>>(qbuf, E, Epart);

    // combine partials -> row stats
    rowstats2<<<dim3(B_DIM * N_DIM / 64), blk, 0, stream>>>(Epart, rmax, rinv);

    // D = h - (val @ att)/colsum  (512-thread, 2-deep pipelined PV)
    pv_mfma<<<dim3(N_DIM / NT, 1, B_DIM), dim3(512), 0, stream>>>(
        valbf, E, rmax, rinv, hp, shp, dbuf);

    // out_i = h + relu(bn_i(Wt_i @ d + bt_i))  (3-product split MFMA)
    gemm_mfma<true><<<dim3(N_DIM / 64, 2, B_DIM), blk, 0, stream>>>(
        wthi + (long long)i * WSZ, wtlo + (long long)i * WSZ, dbuf, CN, nullptr, 0,
        bt + i * C_DIM, bng + i * C_DIM, bnb + i * C_DIM, bnm + i * C_DIM,
        bnv + i * C_DIM, hp, shp, out + (long long)i * CN, nullptr, 4 * CN);
  }
}

// Round 11
// 814.929 us; speedup vs baseline: 1.1426x; 1.1426x over previous
//
#include <hip/hip_runtime.h>
#include <hip/hip_bf16.h>
#include <math.h>

#define B_DIM 8
#define C_DIM 256
#define N_DIM 2048
#define CQ 64

#define TM 64
#define TN 64
#define TK 16

#define NT 32  // pv n-tile

using short8 = __attribute__((ext_vector_type(8))) short;
using f32x4 = __attribute__((ext_vector_type(4))) float;

__device__ __forceinline__ unsigned short f2bf(float x) {
  union { float f; unsigned int u; } c; c.f = x;
  unsigned int r = c.u + 0x7fffu + ((c.u >> 16) & 1u);
  return (unsigned short)(r >> 16);
}
__device__ __forceinline__ float bf2f(unsigned short u) {
  union { unsigned int ui; float f; } c; c.ui = ((unsigned int)u) << 16;
  return c.f;
}

// split fp32 -> (hi, lo) bf16 pair: v ~= hi + lo
__global__ void split_kernel(const float* __restrict__ src, unsigned short* __restrict__ hi,
                             unsigned short* __restrict__ lo, int count) {
  int i = blockIdx.x * 256 + threadIdx.x;
  if (i < count) {
    float v = src[i];
    unsigned short h = f2bf(v);
    hi[i] = h;
    lo[i] = f2bf(v - bf2f(h));
  }
}

// pos[b,c,n] = sum_i w[c,i]*xyz[b,n,i]
__global__ void pos_kernel(const float* __restrict__ w, const float* __restrict__ xyz,
                           float* __restrict__ pos) {
  int n = blockIdx.x * blockDim.x + threadIdx.x;
  int c = blockIdx.y;
  int b = blockIdx.z;
  const float* xp = xyz + ((long long)b * N_DIM + n) * 3;
  pos[((long long)b * C_DIM + c) * N_DIM + n] =
      w[c * 3 + 0] * xp[0] + w[c * 3 + 1] * xp[1] + w[c * 3 + 2] * xp[2];
}

// fp32 VALU GEMM (kept only for the small q projection, M=64)
__global__ void gemm_wx(const float* __restrict__ W,
                        const float* __restrict__ X, long long sxB,
                        const float* __restrict__ Xadd, long long saB,
                        const float* __restrict__ bias,
                        const float* __restrict__ bng, const float* __restrict__ bnb,
                        const float* __restrict__ bnm, const float* __restrict__ bnv,
                        const float* __restrict__ Res, long long srB,
                        float* __restrict__ Y, unsigned short* __restrict__ Ybf,
                        long long syB, int M, int K) {
  const int N = N_DIM;
  int b = blockIdx.z;
  int m0 = blockIdx.y * TM;
  int n0 = blockIdx.x * TN;
  int t = threadIdx.x;
  int tx = t & 15, ty = t >> 4;
  __shared__ float As[TK][TM + 1];
  __shared__ float Bs[TK][TN];
  float acc[4][4] = {};
  const float* Xb = X + (long long)b * sxB;
  const float* Ab = Xadd ? Xadd + (long long)b * saB : nullptr;
  for (int k0 = 0; k0 < K; k0 += TK) {
#pragma unroll
    for (int v = 0; v < 4; v++) {
      int l = t * 4 + v;
      int i = l >> 4, k = l & 15;
      As[k][i] = W[(long long)(m0 + i) * K + k0 + k];
    }
#pragma unroll
    for (int v = 0; v < 4; v++) {
      int l = t * 4 + v;
      int k = l >> 6, j = l & 63;
      float x = Xb[(long long)(k0 + k) * N + n0 + j];
      if (Ab) x += Ab[(long long)(k0 + k) * N + n0 + j];
      Bs[k][j] = x;
    }
    __syncthreads();
#pragma unroll
    for (int k = 0; k < TK; k++) {
      float a[4], bb[4];
#pragma unroll
      for (int ii = 0; ii < 4; ii++) a[ii] = As[k][ty * 4 + ii];
#pragma unroll
      for (int jj = 0; jj < 4; jj++) bb[jj] = Bs[k][tx * 4 + jj];
#pragma unroll
      for (int ii = 0; ii < 4; ii++)
#pragma unroll
        for (int jj = 0; jj < 4; jj++)
          acc[ii][jj] = fmaf(a[ii], bb[jj], acc[ii][jj]);
    }
    __syncthreads();
  }
#pragma unroll
  for (int ii = 0; ii < 4; ii++) {
    int m = m0 + ty * 4 + ii;
    float sh = bias ? bias[m] : 0.f;
    bool dobn = (bng != nullptr);
    float bnsc = 0.f, bnsh = 0.f;
    if (dobn) {
      bnsc = bng[m] * rsqrtf(bnv[m] + 1e-5f);
      bnsh = bnb[m] - bnm[m] * bnsc;
    }
#pragma unroll
    for (int jj = 0; jj < 4; jj++) {
      int n = n0 + tx * 4 + jj;
      float v = acc[ii][jj] + sh;
      if (dobn) v = fmaxf(v * bnsc + bnsh, 0.f);
      if (Res) v += Res[(long long)b * srB + (long long)m * N + n];
      if (Ybf)
        Ybf[(long long)b * syB + (long long)m * N + n] = f2bf(v);
      else
        Y[(long long)b * syB + (long long)m * N + n] = v;
    }
  }
}

// Y[b,m,n] = epi( sum_k W[m,k]*(X[b,k,n]+Xadd) ) via split-bf16 MFMA.
// XLO=true: 3 products (near-fp32). XLO=false: X hi-only (2 products) for bf16 outs.
template <bool XLO>
__global__ __launch_bounds__(256) void gemm_mfma(
    const unsigned short* __restrict__ Whi, const unsigned short* __restrict__ Wlo,
    const float* __restrict__ X, long long sxB,
    const float* __restrict__ Xadd, long long saB,
    const float* __restrict__ bias,
    const float* __restrict__ bng, const float* __restrict__ bnb,
    const float* __restrict__ bnm, const float* __restrict__ bnv,
    const float* __restrict__ Res, long long srB,
    float* __restrict__ Y, unsigned short* __restrict__ Ybf, long long syB) {
  const int N = N_DIM, K = C_DIM;
  int b = blockIdx.z;
  int m0 = blockIdx.y * 128;
  int n0 = blockIdx.x * 64;
  int t = threadIdx.x;
  int w = t >> 6, l = t & 63;
  int lr = l & 15, lk = l >> 4;
  int j = t & 63, dq = t >> 6;   // B staging: col j, k-16-group dq
  int ar = t >> 3, as_ = t & 7;  // A staging: row-slot, k-octet

  __shared__ __align__(16) char Ah[128 * 128];  // [128 m][64 k] bf16, swizzled
  __shared__ __align__(16) char Al[128 * 128];
  __shared__ __align__(16) char Bh[64 * 128];  // [64 n][64 k] bf16, swizzled
  __shared__ __align__(16) char Bl[XLO ? 64 * 128 : 16];

  const float* Xb = X + (long long)b * sxB;
  const float* Adb = Xadd ? Xadd + (long long)b * saB : nullptr;

  f32x4 acc[2][4];
#pragma unroll
  for (int i = 0; i < 2; i++)
#pragma unroll
    for (int jq = 0; jq < 4; jq++) acc[i][jq] = f32x4{0.f, 0.f, 0.f, 0.f};

  for (int k0 = 0; k0 < K; k0 += 64) {
    short8 wh[4], wl[4];
#pragma unroll
    for (int it = 0; it < 4; it++) {
      int r = it * 32 + ar;
      wh[it] = *(const short8*)(Whi + (long long)(m0 + r) * K + k0 + as_ * 8);
      wl[it] = *(const short8*)(Wlo + (long long)(m0 + r) * K + k0 + as_ * 8);
    }
    float v[16];
#pragma unroll
    for (int i = 0; i < 16; i++) {
      float x = Xb[(long long)(k0 + dq * 16 + i) * N + n0 + j];
      if (Adb) x += Adb[(long long)(k0 + dq * 16 + i) * N + n0 + j];
      v[i] = x;
    }
    unsigned int ph[8], pl[8];
#pragma unroll
    for (int i = 0; i < 8; i++) {
      unsigned short h0 = f2bf(v[2 * i]), h1 = f2bf(v[2 * i + 1]);
      ph[i] = (unsigned int)h0 | ((unsigned int)h1 << 16);
      if (XLO) {
        unsigned short l0 = f2bf(v[2 * i] - bf2f(h0)), l1 = f2bf(v[2 * i + 1] - bf2f(h1));
        pl[i] = (unsigned int)l0 | ((unsigned int)l1 << 16);
      }
    }
#pragma unroll
    for (int it = 0; it < 4; it++) {
      int r = it * 32 + ar;
      *(short8*)(Ah + r * 128 + ((as_ ^ (r & 7)) << 4)) = wh[it];
      *(short8*)(Al + r * 128 + ((as_ ^ (r & 7)) << 4)) = wl[it];
    }
    {
      int o0 = dq * 2, o1 = dq * 2 + 1;
      *(uint4*)(Bh + j * 128 + ((o0 ^ (j & 7)) << 4)) = make_uint4(ph[0], ph[1], ph[2], ph[3]);
      *(uint4*)(Bh + j * 128 + ((o1 ^ (j & 7)) << 4)) = make_uint4(ph[4], ph[5], ph[6], ph[7]);
      if (XLO) {
        *(uint4*)(Bl + j * 128 + ((o0 ^ (j & 7)) << 4)) = make_uint4(pl[0], pl[1], pl[2], pl[3]);
        *(uint4*)(Bl + j * 128 + ((o1 ^ (j & 7)) << 4)) = make_uint4(pl[4], pl[5], pl[6], pl[7]);
      }
    }
    __syncthreads();
#pragma unroll
    for (int sub = 0; sub < 2; sub++) {
      short8 ah[2], al2[2], bh[4], bl[4];
#pragma unroll
      for (int mi = 0; mi < 2; mi++) {
        int ra = w * 32 + mi * 16 + lr;
        ah[mi] = *(const short8*)(Ah + ra * 128 + (((sub * 4 + lk) ^ (ra & 7)) << 4));
        al2[mi] = *(const short8*)(Al + ra * 128 + (((sub * 4 + lk) ^ (ra & 7)) << 4));
      }
#pragma unroll
      for (int ni = 0; ni < 4; ni++) {
        int rb = ni * 16 + lr;
        bh[ni] = *(const short8*)(Bh + rb * 128 + (((sub * 4 + lk) ^ (rb & 7)) << 4));
        if (XLO) bl[ni] = *(const short8*)(Bl + rb * 128 + (((sub * 4 + lk) ^ (rb & 7)) << 4));
      }
#pragma unroll
      for (int mi = 0; mi < 2; mi++)
#pragma unroll
        for (int ni = 0; ni < 4; ni++) {
          acc[mi][ni] = __builtin_amdgcn_mfma_f32_16x16x32_bf16(ah[mi], bh[ni], acc[mi][ni], 0, 0, 0);
          if (XLO)
            acc[mi][ni] = __builtin_amdgcn_mfma_f32_16x16x32_bf16(ah[mi], bl[ni], acc[mi][ni], 0, 0, 0);
          acc[mi][ni] = __builtin_amdgcn_mfma_f32_16x16x32_bf16(al2[mi], bh[ni], acc[mi][ni], 0, 0, 0);
        }
    }
    __syncthreads();
  }
#pragma unroll
  for (int mi = 0; mi < 2; mi++) {
#pragma unroll
    for (int jj = 0; jj < 4; jj++) {
      int m = m0 + w * 32 + mi * 16 + lk * 4 + jj;
      float sh = bias ? bias[m] : 0.f;
      bool dobn = (bng != nullptr);
      float bnsc = 0.f, bnsh = 0.f;
      if (dobn) {
        bnsc = bng[m] * rsqrtf(bnv[m] + 1e-5f);
        bnsh = bnb[m] - bnm[m] * bnsc;
      }
#pragma unroll
      for (int ni = 0; ni < 4; ni++) {
        int n = n0 + ni * 16 + lr;
        float vv = acc[mi][ni][jj] + sh;
        if (dobn) vv = fmaxf(vv * bnsc + bnsh, 0.f);
        if (Res) vv += Res[(long long)b * srB + (long long)m * N + n];
        if (Ybf)
          Ybf[(long long)b * syB + (long long)m * N + n] = f2bf(vv);
        else
          Y[(long long)b * syB + (long long)m * N + n] = vv;
      }
    }
  }
}

// E[b,r,c] = sum_d q[b,d,r]*q[b,d,c] via split-bf16 MFMA. 64-row x 128-col block
// (two 64-col tiles sharing one staged A). Emits per-(row, 128-col pair) online
// softmax partials to Epart[16][B*N].
__global__ __launch_bounds__(256) void energy_mfma(const float* __restrict__ q,
                                                   float* __restrict__ E,
                                                   float2* __restrict__ Epart) {
  const int N = N_DIM;
  int b = blockIdx.z;
  int r0 = blockIdx.y * 64;
  int cp = blockIdx.x;  // 128-col pair index
  int t = threadIdx.x;
  int w = t >> 6, l = t & 63;
  int lr = l & 15, lk = l >> 4;
  int j = t & 63, dq = t >> 6;

  __shared__ __align__(16) char Ah[64 * 128];
  __shared__ __align__(16) char Al[64 * 128];
  __shared__ __align__(16) char Bh[64 * 128];
  __shared__ __align__(16) char Bl[64 * 128];

  const float* qb = q + (long long)b * CQ * N;
  // stage A once (q columns r0..r0+64, transposed + split)
  {
    float va[16];
#pragma unroll
    for (int i = 0; i < 16; i++) va[i] = qb[(long long)(dq * 16 + i) * N + r0 + j];
    unsigned int pah[8], pal[8];
#pragma unroll
    for (int i = 0; i < 8; i++) {
      unsigned short h0 = f2bf(va[2 * i]), h1 = f2bf(va[2 * i + 1]);
      unsigned short l0 = f2bf(va[2 * i] - bf2f(h0)), l1 = f2bf(va[2 * i + 1] - bf2f(h1));
      pah[i] = (unsigned int)h0 | ((unsigned int)h1 << 16);
      pal[i] = (unsigned int)l0 | ((unsigned int)l1 << 16);
    }
    int o0 = dq * 2, o1 = dq * 2 + 1;
    *(uint4*)(Ah + j * 128 + ((o0 ^ (j & 7)) << 4)) = make_uint4(pah[0], pah[1], pah[2], pah[3]);
    *(uint4*)(Ah + j * 128 + ((o1 ^ (j & 7)) << 4)) = make_uint4(pah[4], pah[5], pah[6], pah[7]);
    *(uint4*)(Al + j * 128 + ((o0 ^ (j & 7)) << 4)) = make_uint4(pal[0], pal[1], pal[2], pal[3]);
    *(uint4*)(Al + j * 128 + ((o1 ^ (j & 7)) << 4)) = make_uint4(pal[4], pal[5], pal[6], pal[7]);
  }

  float mrun[4], srun[4];
#pragma unroll
  for (int jj = 0; jj < 4; jj++) { mrun[jj] = -3.0e38f; srun[jj] = 0.f; }

  for (int ct = 0; ct < 2; ct++) {
    int c0 = cp * 128 + ct * 64;
    float vb_[16];
#pragma unroll
    for (int i = 0; i < 16; i++) vb_[i] = qb[(long long)(dq * 16 + i) * N + c0 + j];
    unsigned int pbh[8], pbl[8];
#pragma unroll
    for (int i = 0; i < 8; i++) {
      unsigned short g0 = f2bf(vb_[2 * i]), g1 = f2bf(vb_[2 * i + 1]);
      unsigned short m0_ = f2bf(vb_[2 * i] - bf2f(g0)), m1 = f2bf(vb_[2 * i + 1] - bf2f(g1));
      pbh[i] = (unsigned int)g0 | ((unsigned int)g1 << 16);
      pbl[i] = (unsigned int)m0_ | ((unsigned int)m1 << 16);
    }
    __syncthreads();  // ct=0: A-stage visible; ct=1: prior MFMA reads of Bh/Bl done
    {
      int o0 = dq * 2, o1 = dq * 2 + 1;
      *(uint4*)(Bh + j * 128 + ((o0 ^ (j & 7)) << 4)) = make_uint4(pbh[0], pbh[1], pbh[2], pbh[3]);
      *(uint4*)(Bh + j * 128 + ((o1 ^ (j & 7)) << 4)) = make_uint4(pbh[4], pbh[5], pbh[6], pbh[7]);
      *(uint4*)(Bl + j * 128 + ((o0 ^ (j & 7)) << 4)) = make_uint4(pbl[0], pbl[1], pbl[2], pbl[3]);
      *(uint4*)(Bl + j * 128 + ((o1 ^ (j & 7)) << 4)) = make_uint4(pbl[4], pbl[5], pbl[6], pbl[7]);
    }
    __syncthreads();

    f32x4 acc[4];
#pragma unroll
    for (int i = 0; i < 4; i++) acc[i] = f32x4{0.f, 0.f, 0.f, 0.f};
#pragma unroll
    for (int sub = 0; sub < 2; sub++) {
      int ra = w * 16 + lr;
      short8 ah = *(const short8*)(Ah + ra * 128 + (((sub * 4 + lk) ^ (ra & 7)) << 4));
      short8 al = *(const short8*)(Al + ra * 128 + (((sub * 4 + lk) ^ (ra & 7)) << 4));
      short8 bh[4], bl[4];
#pragma unroll
      for (int ni = 0; ni < 4; ni++) {
        int rb = ni * 16 + lr;
        bh[ni] = *(const short8*)(Bh + rb * 128 + (((sub * 4 + lk) ^ (rb & 7)) << 4));
        bl[ni] = *(const short8*)(Bl + rb * 128 + (((sub * 4 + lk) ^ (rb & 7)) << 4));
      }
#pragma unroll
      for (int ni = 0; ni < 4; ni++) {
        acc[ni] = __builtin_amdgcn_mfma_f32_16x16x32_bf16(ah, bh[ni], acc[ni], 0, 0, 0);
        acc[ni] = __builtin_amdgcn_mfma_f32_16x16x32_bf16(ah, bl[ni], acc[ni], 0, 0, 0);
        acc[ni] = __builtin_amdgcn_mfma_f32_16x16x32_bf16(al, bh[ni], acc[ni], 0, 0, 0);
      }
    }
    long long base = (long long)b * N * N;
#pragma unroll
    for (int ni = 0; ni < 4; ni++)
#pragma unroll
      for (int jj = 0; jj < 4; jj++)
        E[base + (long long)(r0 + w * 16 + lk * 4 + jj) * N + c0 + ni * 16 + lr] = acc[ni][jj];

    // per-row stats of this 64-col tile, merged online into the running pair stats
#pragma unroll
    for (int jj = 0; jj < 4; jj++) {
      float vmax = fmaxf(fmaxf(acc[0][jj], acc[1][jj]), fmaxf(acc[2][jj], acc[3][jj]));
#pragma unroll
      for (int msk = 1; msk < 16; msk <<= 1) vmax = fmaxf(vmax, __shfl_xor(vmax, msk, 64));
      float ssum = 0.f;
#pragma unroll
      for (int ni = 0; ni < 4; ni++) ssum += __expf(acc[ni][jj] - vmax);
#pragma unroll
      for (int msk = 1; msk < 16; msk <<= 1) ssum += __shfl_xor(ssum, msk, 64);
      float Mn = fmaxf(mrun[jj], vmax);
      srun[jj] = srun[jj] * __expf(mrun[jj] - Mn) + ssum * __expf(vmax - Mn);
      mrun[jj] = Mn;
    }
  }
  const long long BNr = (long long)B_DIM * N_DIM;
  if (lr == 0) {
#pragma unroll
    for (int jj = 0; jj < 4; jj++) {
      long long row = (long long)b * N + r0 + w * 16 + lk * 4 + jj;
      Epart[(long long)cp * BNr + row] = make_float2(mrun[jj], srun[jj]);
    }
  }
}

// combine 16 per-pair partials per row -> rmax, rinv
__global__ void rowstats2(const float2* __restrict__ Epart, float* __restrict__ rmax,
                          float* __restrict__ rinv) {
  const long long BNr = (long long)B_DIM * N_DIM;
  int rloc = threadIdx.x & 63, qd = threadIdx.x >> 6;
  long long row = (long long)blockIdx.x * 64 + rloc;
  float2 v[4];
  float m = -3.4e38f;
#pragma unroll
  for (int i = 0; i < 4; i++) {
    v[i] = Epart[(long long)(qd * 4 + i) * BNr + row];
    m = fmaxf(m, v[i].x);
  }
  float s = 0.f;
#pragma unroll
  for (int i = 0; i < 4; i++) s += v[i].y * __expf(v[i].x - m);
  __shared__ float sm[4][64], ss[4][64];
  sm[qd][rloc] = m;
  ss[qd][rloc] = s;
  __syncthreads();
  if (qd == 0) {
    float M = fmaxf(fmaxf(sm[0][rloc], sm[1][rloc]), fmaxf(sm[2][rloc], sm[3][rloc]));
    float S = ss[0][rloc] * __expf(sm[0][rloc] - M) + ss[1][rloc] * __expf(sm[1][rloc] - M) +
              ss[2][rloc] * __expf(sm[2][rloc] - M) + ss[3][rloc] * __expf(sm[3][rloc] - M);
    rmax[row] = M;
    rinv[row] = 1.0f / S;
  }
}

// D[b,c,n] = Hprev - (val @ att)/colsum; att built on the fly from E rows (symmetry).
// 512 threads / 8 waves: wave w owns c-rows [w*32, w*32+32). Val + E loads for the
// next k-tile are issued before the MFMA phase (1-deep pipeline; proven 52.7 us).
__global__ __launch_bounds__(512, 4) void pv_mfma(
    const unsigned short* __restrict__ valbf,
    const float* __restrict__ E,
    const float* __restrict__ rmax, const float* __restrict__ rinv,
    const float* __restrict__ Hprev, long long shB, float* __restrict__ D) {
  const int N = N_DIM;
  int b = blockIdx.z;
  int n0 = blockIdx.x * NT;
  int t = threadIdx.x;
  int w = t >> 6, l = t & 63;
  int lr = l & 15, lk = l >> 4;
  int brow = t >> 4, kq = t & 15;  // B-build: n-row 0..31, k-quad 0..15

  __shared__ __align__(16) char As[C_DIM * 128];  // 32 KB val tile
  __shared__ __align__(16) char Bs[NT * 128];     // 4 KB P tile
  __shared__ float csfin[NT];

  const unsigned short* vb = valbf + (long long)b * C_DIM * N;
  const float* Ebr = E + ((long long)b * N + n0 + brow) * N;
  const float* rm = rmax + (long long)b * N;
  const float* ri = rinv + (long long)b * N;

  f32x4 acc[2][2];
#pragma unroll
  for (int i = 0; i < 2; i++)
#pragma unroll
    for (int jq = 0; jq < 2; jq++) acc[i][jq] = f32x4{0.f, 0.f, 0.f, 0.f};
  float cs = 0.f;

  const int kl = kq * 4;
  // prologue: tile-0 registers
  float4 ev = *(const float4*)(Ebr + kl);
  float4 rv = *(const float4*)(rm + kl);
  float4 iv = *(const float4*)(ri + kl);
  short8 areg[4];
#pragma unroll
  for (int it = 0; it < 4; it++) {
    int idx = it * 512 + t;
    int r = idx >> 3, s = idx & 7;
    areg[it] = *(const short8*)(vb + (long long)r * N + s * 8);
  }

  for (int k0 = 0; k0 < N; k0 += 64) {
    __syncthreads();  // prior MFMA reads of As/Bs complete
    // B: att values from regs -> swizzled P tile; accumulate colsum (bf16-rounded)
    {
      float a0 = __expf(ev.x - rv.x) * iv.x;
      float a1 = __expf(ev.y - rv.y) * iv.y;
      float a2 = __expf(ev.z - rv.z) * iv.z;
      float a3 = __expf(ev.w - rv.w) * iv.w;
      unsigned short u0 = f2bf(a0), u1 = f2bf(a1), u2 = f2bf(a2), u3 = f2bf(a3);
      cs += bf2f(u0) + bf2f(u1) + bf2f(u2) + bf2f(u3);
      uint2 pk;
      pk.x = (unsigned int)u0 | ((unsigned int)u1 << 16);
      pk.y = (unsigned int)u2 | ((unsigned int)u3 << 16);
      *(uint2*)(Bs + brow * 128 + ((((kl >> 3) ^ (brow & 7)) << 4) | ((kl & 7) * 2))) = pk;
    }
    // A: val regs -> swizzled LDS
#pragma unroll
    for (int it = 0; it < 4; it++) {
      int idx = it * 512 + t;
      int r = idx >> 3, s = idx & 7;
      *(short8*)(As + r * 128 + ((s ^ (r & 7)) << 4)) = areg[it];
    }
    __syncthreads();
    // prefetch next tile (in flight under the MFMA phase)
    if (k0 + 64 < N) {
      int kb = k0 + 64;
      ev = *(const float4*)(Ebr + kb + kl);
      rv = *(const float4*)(rm + kb + kl);
      iv = *(const float4*)(ri + kb + kl);
#pragma unroll
      for (int it = 0; it < 4; it++) {
        int idx = it * 512 + t;
        int r = idx >> 3, s = idx & 7;
        areg[it] = *(const short8*)(vb + (long long)r * N + kb + s * 8);
      }
    }
    // MFMA: 2 sub-K of 32; wave w rows [w*32, w*32+32)
#pragma unroll
    for (int sub = 0; sub < 2; sub++) {
      short8 bq[2];
#pragma unroll
      for (int ni = 0; ni < 2; ni++) {
        int rn = ni * 16 + lr;
        bq[ni] = *(const short8*)(Bs + rn * 128 + (((sub * 4 + lk) ^ (rn & 7)) << 4));
      }
#pragma unroll
      for (int mi = 0; mi < 2; mi++) {
        int ra = w * 32 + mi * 16 + lr;
        short8 af = *(const short8*)(As + ra * 128 + (((sub * 4 + lk) ^ (ra & 7)) << 4));
#pragma unroll
        for (int ni = 0; ni < 2; ni++)
          acc[mi][ni] = __builtin_amdgcn_mfma_f32_16x16x32_bf16(af, bq[ni], acc[mi][ni], 0, 0, 0);
      }
    }
  }

  // colsum: 16 threads per brow are consecutive lanes (kq = l&15) -> xor-reduce
  cs += __shfl_xor(cs, 1, 64);
  cs += __shfl_xor(cs, 2, 64);
  cs += __shfl_xor(cs, 4, 64);
  cs += __shfl_xor(cs, 8, 64);
  if (kq == 0) csfin[brow] = 1.0f / (1e-9f + cs);
  __syncthreads();

  const float* Hb = Hprev + (long long)b * shB;
  float* Db = D + (long long)b * C_DIM * N;
#pragma unroll
  for (int mi = 0; mi < 2; mi++) {
#pragma unroll
    for (int ni = 0; ni < 2; ni++) {
#pragma unroll
      for (int jj = 0; jj < 4; jj++) {
        int cr = w * 32 + mi * 16 + lk * 4 + jj;
        int ml = ni * 16 + lr;
        float xr = acc[mi][ni][jj] * csfin[ml];
        Db[(long long)cr * N + n0 + ml] = Hb[(long long)cr * N + n0 + ml] - xr;
      }
    }
  }
}

extern "C" void kernel_launch(void* const* d_in, const int* in_sizes, int n_in,
                              void* d_out, int out_size, void* d_ws, size_t ws_size,
                              hipStream_t stream) {
  const float* x = (const float*)d_in[0];
  const float* xyz = (const float*)d_in[1];
  const float* conv1_w = (const float*)d_in[2];
  const float* convpos_w = (const float*)d_in[3];
  const float* bn1_g = (const float*)d_in[4];
  const float* bn1_b = (const float*)d_in[5];
  const float* bn1_m = (const float*)d_in[6];
  const float* bn1_v = (const float*)d_in[7];
  const float* Wqk = (const float*)d_in[8];   // [4,64,256]
  const float* Wv = (const float*)d_in[9];    // [4,256,256]
  const float* bv = (const float*)d_in[10];   // [4,256]
  const float* Wt = (const float*)d_in[11];   // [4,256,256]
  const float* bt = (const float*)d_in[12];   // [4,256]
  const float* bng = (const float*)d_in[13];
  const float* bnb = (const float*)d_in[14];
  const float* bnm = (const float*)d_in[15];
  const float* bnv = (const float*)d_in[16];
  float* out = (float*)d_out;

  const long long BCN = (long long)B_DIM * C_DIM * N_DIM;
  const long long CN = (long long)C_DIM * N_DIM;
  const long long BN = (long long)B_DIM * N_DIM;
  const int WSZ = C_DIM * C_DIM;  // 65536
  float* ws = (float*)d_ws;
  float* pos = ws;                                       // BCN
  float* h0 = pos + BCN;                                 // BCN
  float* qbuf = h0 + BCN;                                // B*CQ*N
  float* dbuf = qbuf + (long long)B_DIM * CQ * N_DIM;    // BCN
  float* rmax = dbuf + BCN;                              // B*N
  float* rinv = rmax + BN;                               // B*N
  unsigned short* valbf = (unsigned short*)(rinv + BN);  // BCN bf16
  unsigned short* whi = valbf + BCN;                     // 9*65536 bf16
  unsigned short* wlo = whi + 9 * WSZ;                   // 9*65536 bf16
  float2* Epart = (float2*)(wlo + 9 * WSZ);              // 32 * B*N float2 (4 MB)
  float* E = (float*)(Epart + 32 * BN);                  // B*N*N

  // whi/wlo layout: [0]=conv1, [1..4]=Wv_i, [5..8]=Wt_i
  unsigned short* c1hi = whi;
  unsigned short* c1lo = wlo;
  unsigned short* wvhi = whi + WSZ;
  unsigned short* wvlo = wlo + WSZ;
  unsigned short* wthi = whi + 5 * WSZ;
  unsigned short* wtlo = wlo + 5 * WSZ;

  dim3 blk(256);

  split_kernel<<<dim3(WSZ / 256), blk, 0, stream>>>(conv1_w, c1hi, c1lo, WSZ);
  split_kernel<<<dim3(4 * WSZ / 256), blk, 0, stream>>>(Wv, wvhi, wvlo, 4 * WSZ);
  split_kernel<<<dim3(4 * WSZ / 256), blk, 0, stream>>>(Wt, wthi, wtlo, 4 * WSZ);

  pos_kernel<<<dim3(N_DIM / 256, C_DIM, B_DIM), blk, 0, stream>>>(convpos_w, xyz, pos);

  // h0 = relu(bn1(conv1_w @ x))   (3-product split MFMA)
  gemm_mfma<true><<<dim3(N_DIM / 64, 2, B_DIM), blk, 0, stream>>>(
      c1hi, c1lo, x, CN, nullptr, 0, nullptr,
      bn1_g, bn1_b, bn1_m, bn1_v, nullptr, 0, h0, nullptr, CN);

  for (int i = 0; i < 4; i++) {
    const float* hp = (i == 0) ? h0 : out + (long long)(i - 1) * CN;
    long long shp = (i == 0) ? CN : 4 * CN;

    // q = Wqk_i @ (h + pos)   (fp32 VALU, exact)
    gemm_wx<<<dim3(N_DIM / TN, CQ / TM, B_DIM), blk, 0, stream>>>(
        Wqk + (long long)i * CQ * C_DIM, hp, shp, pos, CN, nullptr,
        nullptr, nullptr, nullptr, nullptr, nullptr, 0,
        qbuf, nullptr, (long long)CQ * N_DIM, CQ, C_DIM);

    // val = Wv_i @ (h + pos) + bv_i  (2-product: output is bf16-rounded anyway)
    gemm_mfma<false><<<dim3(N_DIM / 64, 2, B_DIM), blk, 0, stream>>>(
        wvhi + (long long)i * WSZ, wvlo + (long long)i * WSZ, hp, shp, pos, CN,
        bv + i * C_DIM, nullptr, nullptr, nullptr, nullptr, nullptr, 0,
        nullptr, valbf, CN);

    // E = q^T q  + per-pair softmax partials (64x128 blocks)
    energy_mfma<<<dim3(N_DIM / 128, N_DIM / 64, B_DIM), blk, 0, stream>>>(qbuf, E, Epart);

    // combine partials -> row stats
    rowstats2<<<dim3(B_DIM * N_DIM / 64), blk, 0, stream>>>(Epart, rmax, rinv);

    // D = h - (val @ att)/colsum  (512-thread, 1-deep pipelined PV)
    pv_mfma<<<dim3(N_DIM / NT, 1, B_DIM), dim3(512), 0, stream>>>(
        valbf, E, rmax, rinv, hp, shp, dbuf);

    // out_i = h + relu(bn_i(Wt_i @ d + bt_i))  (3-product split MFMA)
    gemm_mfma<true><<<dim3(N_DIM / 64, 2, B_DIM), blk, 0, stream>>>(
        wthi + (long long)i * WSZ, wtlo + (long long)i * WSZ, dbuf, CN, nullptr, 0,
        bt + i * C_DIM, bng + i * C_DIM, bnb + i * C_DIM, bnm + i * C_DIM,
        bnv + i * C_DIM, hp, shp, out + (long long)i * CN, nullptr, 4 * CN);
  }
}

// Round 12
// 781.679 us; speedup vs baseline: 1.1912x; 1.0425x over previous
//
#include <hip/hip_runtime.h>
#include <hip/hip_bf16.h>
#include <math.h>

#define B_DIM 8
#define C_DIM 256
#define N_DIM 2048
#define CQ 64

#define TM 64
#define TN 64
#define TK 16

#define NT 32  // pv n-tile

using short8 = __attribute__((ext_vector_type(8))) short;
using f32x4 = __attribute__((ext_vector_type(4))) float;

__device__ __forceinline__ unsigned short f2bf(float x) {
  union { float f; unsigned int u; } c; c.f = x;
  unsigned int r = c.u + 0x7fffu + ((c.u >> 16) & 1u);
  return (unsigned short)(r >> 16);
}
__device__ __forceinline__ float bf2f(unsigned short u) {
  union { unsigned int ui; float f; } c; c.ui = ((unsigned int)u) << 16;
  return c.f;
}
__device__ __forceinline__ unsigned short f2h(float x) {
  union { _Float16 h; unsigned short u; } c;
  c.h = (_Float16)x;
  return c.u;
}
__device__ __forceinline__ float h2f(unsigned short u) {
  union { _Float16 h; unsigned short u; } c;
  c.u = u;
  return (float)c.h;
}

// split fp32 -> (hi, lo) bf16 pair: v ~= hi + lo
__global__ void split_kernel(const float* __restrict__ src, unsigned short* __restrict__ hi,
                             unsigned short* __restrict__ lo, int count) {
  int i = blockIdx.x * 256 + threadIdx.x;
  if (i < count) {
    float v = src[i];
    unsigned short h = f2bf(v);
    hi[i] = h;
    lo[i] = f2bf(v - bf2f(h));
  }
}

// pos[b,c,n] = sum_i w[c,i]*xyz[b,n,i]
__global__ void pos_kernel(const float* __restrict__ w, const float* __restrict__ xyz,
                           float* __restrict__ pos) {
  int n = blockIdx.x * blockDim.x + threadIdx.x;
  int c = blockIdx.y;
  int b = blockIdx.z;
  const float* xp = xyz + ((long long)b * N_DIM + n) * 3;
  pos[((long long)b * C_DIM + c) * N_DIM + n] =
      w[c * 3 + 0] * xp[0] + w[c * 3 + 1] * xp[1] + w[c * 3 + 2] * xp[2];
}

// fp32 VALU GEMM (kept only for the small q projection, M=64)
__global__ void gemm_wx(const float* __restrict__ W,
                        const float* __restrict__ X, long long sxB,
                        const float* __restrict__ Xadd, long long saB,
                        const float* __restrict__ bias,
                        const float* __restrict__ bng, const float* __restrict__ bnb,
                        const float* __restrict__ bnm, const float* __restrict__ bnv,
                        const float* __restrict__ Res, long long srB,
                        float* __restrict__ Y, unsigned short* __restrict__ Ybf,
                        long long syB, int M, int K) {
  const int N = N_DIM;
  int b = blockIdx.z;
  int m0 = blockIdx.y * TM;
  int n0 = blockIdx.x * TN;
  int t = threadIdx.x;
  int tx = t & 15, ty = t >> 4;
  __shared__ float As[TK][TM + 1];
  __shared__ float Bs[TK][TN];
  float acc[4][4] = {};
  const float* Xb = X + (long long)b * sxB;
  const float* Ab = Xadd ? Xadd + (long long)b * saB : nullptr;
  for (int k0 = 0; k0 < K; k0 += TK) {
#pragma unroll
    for (int v = 0; v < 4; v++) {
      int l = t * 4 + v;
      int i = l >> 4, k = l & 15;
      As[k][i] = W[(long long)(m0 + i) * K + k0 + k];
    }
#pragma unroll
    for (int v = 0; v < 4; v++) {
      int l = t * 4 + v;
      int k = l >> 6, j = l & 63;
      float x = Xb[(long long)(k0 + k) * N + n0 + j];
      if (Ab) x += Ab[(long long)(k0 + k) * N + n0 + j];
      Bs[k][j] = x;
    }
    __syncthreads();
#pragma unroll
    for (int k = 0; k < TK; k++) {
      float a[4], bb[4];
#pragma unroll
      for (int ii = 0; ii < 4; ii++) a[ii] = As[k][ty * 4 + ii];
#pragma unroll
      for (int jj = 0; jj < 4; jj++) bb[jj] = Bs[k][tx * 4 + jj];
#pragma unroll
      for (int ii = 0; ii < 4; ii++)
#pragma unroll
        for (int jj = 0; jj < 4; jj++)
          acc[ii][jj] = fmaf(a[ii], bb[jj], acc[ii][jj]);
    }
    __syncthreads();
  }
#pragma unroll
  for (int ii = 0; ii < 4; ii++) {
    int m = m0 + ty * 4 + ii;
    float sh = bias ? bias[m] : 0.f;
    bool dobn = (bng != nullptr);
    float bnsc = 0.f, bnsh = 0.f;
    if (dobn) {
      bnsc = bng[m] * rsqrtf(bnv[m] + 1e-5f);
      bnsh = bnb[m] - bnm[m] * bnsc;
    }
#pragma unroll
    for (int jj = 0; jj < 4; jj++) {
      int n = n0 + tx * 4 + jj;
      float v = acc[ii][jj] + sh;
      if (dobn) v = fmaxf(v * bnsc + bnsh, 0.f);
      if (Res) v += Res[(long long)b * srB + (long long)m * N + n];
      if (Ybf)
        Ybf[(long long)b * syB + (long long)m * N + n] = f2bf(v);
      else
        Y[(long long)b * syB + (long long)m * N + n] = v;
    }
  }
}

// Y[b,m,n] = epi( sum_k W[m,k]*(X[b,k,n]+Xadd) ) via split-bf16 MFMA.
// XLO=true: 3 products (near-fp32). XLO=false: X hi-only (2 products) for bf16 outs.
template <bool XLO>
__global__ __launch_bounds__(256) void gemm_mfma(
    const unsigned short* __restrict__ Whi, const unsigned short* __restrict__ Wlo,
    const float* __restrict__ X, long long sxB,
    const float* __restrict__ Xadd, long long saB,
    const float* __restrict__ bias,
    const float* __restrict__ bng, const float* __restrict__ bnb,
    const float* __restrict__ bnm, const float* __restrict__ bnv,
    const float* __restrict__ Res, long long srB,
    float* __restrict__ Y, unsigned short* __restrict__ Ybf, long long syB) {
  const int N = N_DIM, K = C_DIM;
  int b = blockIdx.z;
  int m0 = blockIdx.y * 128;
  int n0 = blockIdx.x * 64;
  int t = threadIdx.x;
  int w = t >> 6, l = t & 63;
  int lr = l & 15, lk = l >> 4;
  int j = t & 63, dq = t >> 6;   // B staging: col j, k-16-group dq
  int ar = t >> 3, as_ = t & 7;  // A staging: row-slot, k-octet

  __shared__ __align__(16) char Ah[128 * 128];  // [128 m][64 k] bf16, swizzled
  __shared__ __align__(16) char Al[128 * 128];
  __shared__ __align__(16) char Bh[64 * 128];  // [64 n][64 k] bf16, swizzled
  __shared__ __align__(16) char Bl[XLO ? 64 * 128 : 16];

  const float* Xb = X + (long long)b * sxB;
  const float* Adb = Xadd ? Xadd + (long long)b * saB : nullptr;

  f32x4 acc[2][4];
#pragma unroll
  for (int i = 0; i < 2; i++)
#pragma unroll
    for (int jq = 0; jq < 4; jq++) acc[i][jq] = f32x4{0.f, 0.f, 0.f, 0.f};

  for (int k0 = 0; k0 < K; k0 += 64) {
    short8 wh[4], wl[4];
#pragma unroll
    for (int it = 0; it < 4; it++) {
      int r = it * 32 + ar;
      wh[it] = *(const short8*)(Whi + (long long)(m0 + r) * K + k0 + as_ * 8);
      wl[it] = *(const short8*)(Wlo + (long long)(m0 + r) * K + k0 + as_ * 8);
    }
    float v[16];
#pragma unroll
    for (int i = 0; i < 16; i++) {
      float x = Xb[(long long)(k0 + dq * 16 + i) * N + n0 + j];
      if (Adb) x += Adb[(long long)(k0 + dq * 16 + i) * N + n0 + j];
      v[i] = x;
    }
    unsigned int ph[8], pl[8];
#pragma unroll
    for (int i = 0; i < 8; i++) {
      unsigned short h0 = f2bf(v[2 * i]), h1 = f2bf(v[2 * i + 1]);
      ph[i] = (unsigned int)h0 | ((unsigned int)h1 << 16);
      if (XLO) {
        unsigned short l0 = f2bf(v[2 * i] - bf2f(h0)), l1 = f2bf(v[2 * i + 1] - bf2f(h1));
        pl[i] = (unsigned int)l0 | ((unsigned int)l1 << 16);
      }
    }
#pragma unroll
    for (int it = 0; it < 4; it++) {
      int r = it * 32 + ar;
      *(short8*)(Ah + r * 128 + ((as_ ^ (r & 7)) << 4)) = wh[it];
      *(short8*)(Al + r * 128 + ((as_ ^ (r & 7)) << 4)) = wl[it];
    }
    {
      int o0 = dq * 2, o1 = dq * 2 + 1;
      *(uint4*)(Bh + j * 128 + ((o0 ^ (j & 7)) << 4)) = make_uint4(ph[0], ph[1], ph[2], ph[3]);
      *(uint4*)(Bh + j * 128 + ((o1 ^ (j & 7)) << 4)) = make_uint4(ph[4], ph[5], ph[6], ph[7]);
      if (XLO) {
        *(uint4*)(Bl + j * 128 + ((o0 ^ (j & 7)) << 4)) = make_uint4(pl[0], pl[1], pl[2], pl[3]);
        *(uint4*)(Bl + j * 128 + ((o1 ^ (j & 7)) << 4)) = make_uint4(pl[4], pl[5], pl[6], pl[7]);
      }
    }
    __syncthreads();
#pragma unroll
    for (int sub = 0; sub < 2; sub++) {
      short8 ah[2], al2[2], bh[4], bl[4];
#pragma unroll
      for (int mi = 0; mi < 2; mi++) {
        int ra = w * 32 + mi * 16 + lr;
        ah[mi] = *(const short8*)(Ah + ra * 128 + (((sub * 4 + lk) ^ (ra & 7)) << 4));
        al2[mi] = *(const short8*)(Al + ra * 128 + (((sub * 4 + lk) ^ (ra & 7)) << 4));
      }
#pragma unroll
      for (int ni = 0; ni < 4; ni++) {
        int rb = ni * 16 + lr;
        bh[ni] = *(const short8*)(Bh + rb * 128 + (((sub * 4 + lk) ^ (rb & 7)) << 4));
        if (XLO) bl[ni] = *(const short8*)(Bl + rb * 128 + (((sub * 4 + lk) ^ (rb & 7)) << 4));
      }
#pragma unroll
      for (int mi = 0; mi < 2; mi++)
#pragma unroll
        for (int ni = 0; ni < 4; ni++) {
          acc[mi][ni] = __builtin_amdgcn_mfma_f32_16x16x32_bf16(ah[mi], bh[ni], acc[mi][ni], 0, 0, 0);
          if (XLO)
            acc[mi][ni] = __builtin_amdgcn_mfma_f32_16x16x32_bf16(ah[mi], bl[ni], acc[mi][ni], 0, 0, 0);
          acc[mi][ni] = __builtin_amdgcn_mfma_f32_16x16x32_bf16(al2[mi], bh[ni], acc[mi][ni], 0, 0, 0);
        }
    }
    __syncthreads();
  }
#pragma unroll
  for (int mi = 0; mi < 2; mi++) {
#pragma unroll
    for (int jj = 0; jj < 4; jj++) {
      int m = m0 + w * 32 + mi * 16 + lk * 4 + jj;
      float sh = bias ? bias[m] : 0.f;
      bool dobn = (bng != nullptr);
      float bnsc = 0.f, bnsh = 0.f;
      if (dobn) {
        bnsc = bng[m] * rsqrtf(bnv[m] + 1e-5f);
        bnsh = bnb[m] - bnm[m] * bnsc;
      }
#pragma unroll
      for (int ni = 0; ni < 4; ni++) {
        int n = n0 + ni * 16 + lr;
        float vv = acc[mi][ni][jj] + sh;
        if (dobn) vv = fmaxf(vv * bnsc + bnsh, 0.f);
        if (Res) vv += Res[(long long)b * srB + (long long)m * N + n];
        if (Ybf)
          Ybf[(long long)b * syB + (long long)m * N + n] = f2bf(vv);
        else
          Y[(long long)b * syB + (long long)m * N + n] = vv;
      }
    }
  }
}

// E[b,r,c] = sum_d q[b,d,r]*q[b,d,c] via split-bf16 MFMA; E stored as fp16.
// 64-row x 128-col block (two 64-col tiles sharing one staged A). Emits per-
// (row, 128-col pair) online softmax partials to Epart[16][B*N].
__global__ __launch_bounds__(256) void energy_mfma(const float* __restrict__ q,
                                                   unsigned short* __restrict__ Eh,
                                                   float2* __restrict__ Epart) {
  const int N = N_DIM;
  int b = blockIdx.z;
  int r0 = blockIdx.y * 64;
  int cp = blockIdx.x;  // 128-col pair index
  int t = threadIdx.x;
  int w = t >> 6, l = t & 63;
  int lr = l & 15, lk = l >> 4;
  int j = t & 63, dq = t >> 6;

  __shared__ __align__(16) char Ah[64 * 128];
  __shared__ __align__(16) char Al[64 * 128];
  __shared__ __align__(16) char Bh[64 * 128];
  __shared__ __align__(16) char Bl[64 * 128];

  const float* qb = q + (long long)b * CQ * N;
  // stage A once (q columns r0..r0+64, transposed + split)
  {
    float va[16];
#pragma unroll
    for (int i = 0; i < 16; i++) va[i] = qb[(long long)(dq * 16 + i) * N + r0 + j];
    unsigned int pah[8], pal[8];
#pragma unroll
    for (int i = 0; i < 8; i++) {
      unsigned short h0 = f2bf(va[2 * i]), h1 = f2bf(va[2 * i + 1]);
      unsigned short l0 = f2bf(va[2 * i] - bf2f(h0)), l1 = f2bf(va[2 * i + 1] - bf2f(h1));
      pah[i] = (unsigned int)h0 | ((unsigned int)h1 << 16);
      pal[i] = (unsigned int)l0 | ((unsigned int)l1 << 16);
    }
    int o0 = dq * 2, o1 = dq * 2 + 1;
    *(uint4*)(Ah + j * 128 + ((o0 ^ (j & 7)) << 4)) = make_uint4(pah[0], pah[1], pah[2], pah[3]);
    *(uint4*)(Ah + j * 128 + ((o1 ^ (j & 7)) << 4)) = make_uint4(pah[4], pah[5], pah[6], pah[7]);
    *(uint4*)(Al + j * 128 + ((o0 ^ (j & 7)) << 4)) = make_uint4(pal[0], pal[1], pal[2], pal[3]);
    *(uint4*)(Al + j * 128 + ((o1 ^ (j & 7)) << 4)) = make_uint4(pal[4], pal[5], pal[6], pal[7]);
  }

  float mrun[4], srun[4];
#pragma unroll
  for (int jj = 0; jj < 4; jj++) { mrun[jj] = -3.0e38f; srun[jj] = 0.f; }

  for (int ct = 0; ct < 2; ct++) {
    int c0 = cp * 128 + ct * 64;
    float vb_[16];
#pragma unroll
    for (int i = 0; i < 16; i++) vb_[i] = qb[(long long)(dq * 16 + i) * N + c0 + j];
    unsigned int pbh[8], pbl[8];
#pragma unroll
    for (int i = 0; i < 8; i++) {
      unsigned short g0 = f2bf(vb_[2 * i]), g1 = f2bf(vb_[2 * i + 1]);
      unsigned short m0_ = f2bf(vb_[2 * i] - bf2f(g0)), m1 = f2bf(vb_[2 * i + 1] - bf2f(g1));
      pbh[i] = (unsigned int)g0 | ((unsigned int)g1 << 16);
      pbl[i] = (unsigned int)m0_ | ((unsigned int)m1 << 16);
    }
    __syncthreads();  // ct=0: A-stage visible; ct=1: prior MFMA reads of Bh/Bl done
    {
      int o0 = dq * 2, o1 = dq * 2 + 1;
      *(uint4*)(Bh + j * 128 + ((o0 ^ (j & 7)) << 4)) = make_uint4(pbh[0], pbh[1], pbh[2], pbh[3]);
      *(uint4*)(Bh + j * 128 + ((o1 ^ (j & 7)) << 4)) = make_uint4(pbh[4], pbh[5], pbh[6], pbh[7]);
      *(uint4*)(Bl + j * 128 + ((o0 ^ (j & 7)) << 4)) = make_uint4(pbl[0], pbl[1], pbl[2], pbl[3]);
      *(uint4*)(Bl + j * 128 + ((o1 ^ (j & 7)) << 4)) = make_uint4(pbl[4], pbl[5], pbl[6], pbl[7]);
    }
    __syncthreads();

    f32x4 acc[4];
#pragma unroll
    for (int i = 0; i < 4; i++) acc[i] = f32x4{0.f, 0.f, 0.f, 0.f};
#pragma unroll
    for (int sub = 0; sub < 2; sub++) {
      int ra = w * 16 + lr;
      short8 ah = *(const short8*)(Ah + ra * 128 + (((sub * 4 + lk) ^ (ra & 7)) << 4));
      short8 al = *(const short8*)(Al + ra * 128 + (((sub * 4 + lk) ^ (ra & 7)) << 4));
      short8 bh[4], bl[4];
#pragma unroll
      for (int ni = 0; ni < 4; ni++) {
        int rb = ni * 16 + lr;
        bh[ni] = *(const short8*)(Bh + rb * 128 + (((sub * 4 + lk) ^ (rb & 7)) << 4));
        bl[ni] = *(const short8*)(Bl + rb * 128 + (((sub * 4 + lk) ^ (rb & 7)) << 4));
      }
#pragma unroll
      for (int ni = 0; ni < 4; ni++) {
        acc[ni] = __builtin_amdgcn_mfma_f32_16x16x32_bf16(ah, bh[ni], acc[ni], 0, 0, 0);
        acc[ni] = __builtin_amdgcn_mfma_f32_16x16x32_bf16(ah, bl[ni], acc[ni], 0, 0, 0);
        acc[ni] = __builtin_amdgcn_mfma_f32_16x16x32_bf16(al, bh[ni], acc[ni], 0, 0, 0);
      }
    }
    long long base = (long long)b * N * N;
#pragma unroll
    for (int ni = 0; ni < 4; ni++)
#pragma unroll
      for (int jj = 0; jj < 4; jj++)
        Eh[base + (long long)(r0 + w * 16 + lk * 4 + jj) * N + c0 + ni * 16 + lr] =
            f2h(acc[ni][jj]);

    // per-row stats of this 64-col tile, merged online into the running pair stats
#pragma unroll
    for (int jj = 0; jj < 4; jj++) {
      float vmax = fmaxf(fmaxf(acc[0][jj], acc[1][jj]), fmaxf(acc[2][jj], acc[3][jj]));
#pragma unroll
      for (int msk = 1; msk < 16; msk <<= 1) vmax = fmaxf(vmax, __shfl_xor(vmax, msk, 64));
      float ssum = 0.f;
#pragma unroll
      for (int ni = 0; ni < 4; ni++) ssum += __expf(acc[ni][jj] - vmax);
#pragma unroll
      for (int msk = 1; msk < 16; msk <<= 1) ssum += __shfl_xor(ssum, msk, 64);
      float Mn = fmaxf(mrun[jj], vmax);
      srun[jj] = srun[jj] * __expf(mrun[jj] - Mn) + ssum * __expf(vmax - Mn);
      mrun[jj] = Mn;
    }
  }
  const long long BNr = (long long)B_DIM * N_DIM;
  if (lr == 0) {
#pragma unroll
    for (int jj = 0; jj < 4; jj++) {
      long long row = (long long)b * N + r0 + w * 16 + lk * 4 + jj;
      Epart[(long long)cp * BNr + row] = make_float2(mrun[jj], srun[jj]);
    }
  }
}

// combine 16 per-pair partials per row -> rmax, rinv
__global__ void rowstats2(const float2* __restrict__ Epart, float* __restrict__ rmax,
                          float* __restrict__ rinv) {
  const long long BNr = (long long)B_DIM * N_DIM;
  int rloc = threadIdx.x & 63, qd = threadIdx.x >> 6;
  long long row = (long long)blockIdx.x * 64 + rloc;
  float2 v[4];
  float m = -3.4e38f;
#pragma unroll
  for (int i = 0; i < 4; i++) {
    v[i] = Epart[(long long)(qd * 4 + i) * BNr + row];
    m = fmaxf(m, v[i].x);
  }
  float s = 0.f;
#pragma unroll
  for (int i = 0; i < 4; i++) s += v[i].y * __expf(v[i].x - m);
  __shared__ float sm[4][64], ss[4][64];
  sm[qd][rloc] = m;
  ss[qd][rloc] = s;
  __syncthreads();
  if (qd == 0) {
    float M = fmaxf(fmaxf(sm[0][rloc], sm[1][rloc]), fmaxf(sm[2][rloc], sm[3][rloc]));
    float S = ss[0][rloc] * __expf(sm[0][rloc] - M) + ss[1][rloc] * __expf(sm[1][rloc] - M) +
              ss[2][rloc] * __expf(sm[2][rloc] - M) + ss[3][rloc] * __expf(sm[3][rloc] - M);
    rmax[row] = M;
    rinv[row] = 1.0f / S;
  }
}

// D[b,c,n] = Hprev - (val @ att)/colsum; att from fp16 E rows (symmetry) + stats.
// 512 threads / 8 waves; LDS DOUBLE-BUFFER, one barrier per k-tile:
// iter i: COMPUTE(buf i&1) || STAGE(tile i+1 -> buf (i+1)&1) ; LOAD(tile i+2) ; barrier.
#define PV_LOAD(kb)                                                            \
  {                                                                            \
    ev = *(const ushort4*)(Ehr + (kb) + kl);                                   \
    rv = *(const float4*)(rm + (kb) + kl);                                     \
    iv = *(const float4*)(ri + (kb) + kl);                                     \
    _Pragma("unroll") for (int it = 0; it < 4; it++) {                         \
      int idx = it * 512 + t;                                                  \
      int r = idx >> 3, s = idx & 7;                                           \
      areg[it] = *(const short8*)(vb + (long long)r * N + (kb) + s * 8);       \
    }                                                                          \
  }

#define PV_STAGE(bu)                                                           \
  {                                                                            \
    float a0 = __expf(h2f(ev.x) - rv.x) * iv.x;                                \
    float a1 = __expf(h2f(ev.y) - rv.y) * iv.y;                                \
    float a2 = __expf(h2f(ev.z) - rv.z) * iv.z;                                \
    float a3 = __expf(h2f(ev.w) - rv.w) * iv.w;                                \
    unsigned short u0 = f2bf(a0), u1 = f2bf(a1), u2 = f2bf(a2), u3 = f2bf(a3); \
    cs += bf2f(u0) + bf2f(u1) + bf2f(u2) + bf2f(u3);                           \
    uint2 pk;                                                                  \
    pk.x = (unsigned int)u0 | ((unsigned int)u1 << 16);                        \
    pk.y = (unsigned int)u2 | ((unsigned int)u3 << 16);                        \
    *(uint2*)(Bs[bu] + brow * 128 +                                            \
              ((((kl >> 3) ^ (brow & 7)) << 4) | ((kl & 7) * 2))) = pk;        \
    _Pragma("unroll") for (int it = 0; it < 4; it++) {                         \
      int idx = it * 512 + t;                                                  \
      int r = idx >> 3, s = idx & 7;                                           \
      *(short8*)(As[bu] + r * 128 + ((s ^ (r & 7)) << 4)) = areg[it];          \
    }                                                                          \
  }

#define PV_COMPUTE(bu)                                                         \
  _Pragma("unroll") for (int sub = 0; sub < 2; sub++) {                        \
    short8 bq[2];                                                              \
    _Pragma("unroll") for (int ni = 0; ni < 2; ni++) {                         \
      int rn = ni * 16 + lr;                                                   \
      bq[ni] = *(const short8*)(Bs[bu] + rn * 128 +                            \
                                (((sub * 4 + lk) ^ (rn & 7)) << 4));           \
    }                                                                          \
    _Pragma("unroll") for (int mi = 0; mi < 2; mi++) {                         \
      int ra = w * 32 + mi * 16 + lr;                                          \
      short8 af = *(const short8*)(As[bu] + ra * 128 +                         \
                                   (((sub * 4 + lk) ^ (ra & 7)) << 4));        \
      _Pragma("unroll") for (int ni = 0; ni < 2; ni++)                         \
          acc[mi][ni] = __builtin_amdgcn_mfma_f32_16x16x32_bf16(               \
              af, bq[ni], acc[mi][ni], 0, 0, 0);                               \
    }                                                                          \
  }

__global__ __launch_bounds__(512, 4) void pv_mfma(
    const unsigned short* __restrict__ valbf,
    const unsigned short* __restrict__ Eh,
    const float* __restrict__ rmax, const float* __restrict__ rinv,
    const float* __restrict__ Hprev, long long shB, float* __restrict__ D) {
  const int N = N_DIM;
  int b = blockIdx.z;
  int n0 = blockIdx.x * NT;
  int t = threadIdx.x;
  int w = t >> 6, l = t & 63;
  int lr = l & 15, lk = l >> 4;
  int brow = t >> 4, kq = t & 15;  // B-build: n-row 0..31, k-quad 0..15

  __shared__ __align__(16) char As[2][C_DIM * 128];  // 2 x 32 KB val tiles
  __shared__ __align__(16) char Bs[2][NT * 128];     // 2 x 4 KB P tiles
  __shared__ float csfin[NT];

  const unsigned short* vb = valbf + (long long)b * C_DIM * N;
  const unsigned short* Ehr = Eh + ((long long)b * N + n0 + brow) * N;
  const float* rm = rmax + (long long)b * N;
  const float* ri = rinv + (long long)b * N;

  f32x4 acc[2][2];
#pragma unroll
  for (int i = 0; i < 2; i++)
#pragma unroll
    for (int jq = 0; jq < 2; jq++) acc[i][jq] = f32x4{0.f, 0.f, 0.f, 0.f};
  float cs = 0.f;
  const int kl = kq * 4;

  ushort4 ev;
  float4 rv, iv;
  short8 areg[4];

  // prologue: stage tile 0 into buf 0, prefetch tile 1 regs
  PV_LOAD(0);
  PV_STAGE(0);
  PV_LOAD(64);
  __syncthreads();

  const int NTILES = N / 64;  // 32
  for (int i = 0; i < NTILES; i++) {
    int cur = i & 1;
    PV_COMPUTE(cur);
    if (i < NTILES - 1) {
      PV_STAGE(cur ^ 1);                       // tile i+1 (regs) -> other buffer
      if (i < NTILES - 2) PV_LOAD((i + 2) * 64);  // prefetch tile i+2
    }
    __syncthreads();
  }

  // colsum: 16 threads per brow are consecutive lanes (kq = l&15) -> xor-reduce
  cs += __shfl_xor(cs, 1, 64);
  cs += __shfl_xor(cs, 2, 64);
  cs += __shfl_xor(cs, 4, 64);
  cs += __shfl_xor(cs, 8, 64);
  if (kq == 0) csfin[brow] = 1.0f / (1e-9f + cs);
  __syncthreads();

  const float* Hb = Hprev + (long long)b * shB;
  float* Db = D + (long long)b * C_DIM * N;
#pragma unroll
  for (int mi = 0; mi < 2; mi++) {
#pragma unroll
    for (int ni = 0; ni < 2; ni++) {
#pragma unroll
      for (int jj = 0; jj < 4; jj++) {
        int cr = w * 32 + mi * 16 + lk * 4 + jj;
        int ml = ni * 16 + lr;
        float xr = acc[mi][ni][jj] * csfin[ml];
        Db[(long long)cr * N + n0 + ml] = Hb[(long long)cr * N + n0 + ml] - xr;
      }
    }
  }
}

extern "C" void kernel_launch(void* const* d_in, const int* in_sizes, int n_in,
                              void* d_out, int out_size, void* d_ws, size_t ws_size,
                              hipStream_t stream) {
  const float* x = (const float*)d_in[0];
  const float* xyz = (const float*)d_in[1];
  const float* conv1_w = (const float*)d_in[2];
  const float* convpos_w = (const float*)d_in[3];
  const float* bn1_g = (const float*)d_in[4];
  const float* bn1_b = (const float*)d_in[5];
  const float* bn1_m = (const float*)d_in[6];
  const float* bn1_v = (const float*)d_in[7];
  const float* Wqk = (const float*)d_in[8];   // [4,64,256]
  const float* Wv = (const float*)d_in[9];    // [4,256,256]
  const float* bv = (const float*)d_in[10];   // [4,256]
  const float* Wt = (const float*)d_in[11];   // [4,256,256]
  const float* bt = (const float*)d_in[12];   // [4,256]
  const float* bng = (const float*)d_in[13];
  const float* bnb = (const float*)d_in[14];
  const float* bnm = (const float*)d_in[15];
  const float* bnv = (const float*)d_in[16];
  float* out = (float*)d_out;

  const long long BCN = (long long)B_DIM * C_DIM * N_DIM;
  const long long CN = (long long)C_DIM * N_DIM;
  const long long BN = (long long)B_DIM * N_DIM;
  const int WSZ = C_DIM * C_DIM;  // 65536
  float* ws = (float*)d_ws;
  float* pos = ws;                                       // BCN
  float* h0 = pos + BCN;                                 // BCN
  float* qbuf = h0 + BCN;                                // B*CQ*N
  float* dbuf = qbuf + (long long)B_DIM * CQ * N_DIM;    // BCN
  float* rmax = dbuf + BCN;                              // B*N
  float* rinv = rmax + BN;                               // B*N
  unsigned short* valbf = (unsigned short*)(rinv + BN);  // BCN bf16
  unsigned short* whi = valbf + BCN;                     // 9*65536 bf16
  unsigned short* wlo = whi + 9 * WSZ;                   // 9*65536 bf16
  float2* Epart = (float2*)(wlo + 9 * WSZ);              // 32 * B*N float2
  unsigned short* Eh = (unsigned short*)(Epart + 32 * BN);  // B*N*N fp16

  // whi/wlo layout: [0]=conv1, [1..4]=Wv_i, [5..8]=Wt_i
  unsigned short* c1hi = whi;
  unsigned short* c1lo = wlo;
  unsigned short* wvhi = whi + WSZ;
  unsigned short* wvlo = wlo + WSZ;
  unsigned short* wthi = whi + 5 * WSZ;
  unsigned short* wtlo = wlo + 5 * WSZ;

  dim3 blk(256);

  split_kernel<<<dim3(WSZ / 256), blk, 0, stream>>>(conv1_w, c1hi, c1lo, WSZ);
  split_kernel<<<dim3(4 * WSZ / 256), blk, 0, stream>>>(Wv, wvhi, wvlo, 4 * WSZ);
  split_kernel<<<dim3(4 * WSZ / 256), blk, 0, stream>>>(Wt, wthi, wtlo, 4 * WSZ);

  pos_kernel<<<dim3(N_DIM / 256, C_DIM, B_DIM), blk, 0, stream>>>(convpos_w, xyz, pos);

  // h0 = relu(bn1(conv1_w @ x))   (3-product split MFMA)
  gemm_mfma<true><<<dim3(N_DIM / 64, 2, B_DIM), blk, 0, stream>>>(
      c1hi, c1lo, x, CN, nullptr, 0, nullptr,
      bn1_g, bn1_b, bn1_m, bn1_v, nullptr, 0, h0, nullptr, CN);

  for (int i = 0; i < 4; i++) {
    const float* hp = (i == 0) ? h0 : out + (long long)(i - 1) * CN;
    long long shp = (i == 0) ? CN : 4 * CN;

    // q = Wqk_i @ (h + pos)   (fp32 VALU, exact)
    gemm_wx<<<dim3(N_DIM / TN, CQ / TM, B_DIM), blk, 0, stream>>>(
        Wqk + (long long)i * CQ * C_DIM, hp, shp, pos, CN, nullptr,
        nullptr, nullptr, nullptr, nullptr, nullptr, 0,
        qbuf, nullptr, (long long)CQ * N_DIM, CQ, C_DIM);

    // val = Wv_i @ (h + pos) + bv_i  (2-product: output is bf16-rounded anyway)
    gemm_mfma<false><<<dim3(N_DIM / 64, 2, B_DIM), blk, 0, stream>>>(
        wvhi + (long long)i * WSZ, wvlo + (long long)i * WSZ, hp, shp, pos, CN,
        bv + i * C_DIM, nullptr, nullptr, nullptr, nullptr, nullptr, 0,
        nullptr, valbf, CN);

    // E = q^T q (fp16 store) + per-pair softmax partials (64x128 blocks)
    energy_mfma<<<dim3(N_DIM / 128, N_DIM / 64, B_DIM), blk, 0, stream>>>(qbuf, Eh, Epart);

    // combine partials -> row stats
    rowstats2<<<dim3(B_DIM * N_DIM / 64), blk, 0, stream>>>(Epart, rmax, rinv);

    // D = h - (val @ att)/colsum  (512-thread, LDS double-buffered PV)
    pv_mfma<<<dim3(N_DIM / NT, 1, B_DIM), dim3(512), 0, stream>>>(
        valbf, Eh, rmax, rinv, hp, shp, dbuf);

    // out_i = h + relu(bn_i(Wt_i @ d + bt_i))  (3-product split MFMA)
    gemm_mfma<true><<<dim3(N_DIM / 64, 2, B_DIM), blk, 0, stream>>>(
        wthi + (long long)i * WSZ, wtlo + (long long)i * WSZ, dbuf, CN, nullptr, 0,
        bt + i * C_DIM, bng + i * C_DIM, bnb + i * C_DIM, bnm + i * C_DIM,
        bnv + i * C_DIM, hp, shp, out + (long long)i * CN, nullptr, 4 * CN);
  }
}